// Round 7
// baseline (77.026 us; speedup 1.0000x reference)
//
#include <hip/hip_runtime.h>
#include <hip/hip_bf16.h>

// Local attention block: 40^3 volume, C=64, 4 heads of hd=16, 3x3x3 window,
// replicate padding, residual add. f32 in/out.
//
// Kernel 0: pack W (3x[64][64] f32) -> bf16 [192][64] (Q rows pre-scaled by
//           1/4) + packed bias f32[192].
// Kernel 1: FUSED. Per block (2x4x8 own tile):
//           - stage x halo (4x6x10 = 240 vox, bf16) to LDS
//           - MFMA-project K,V for all 240 halo voxels (recompute > refetch),
//             Q for own 64 voxels; V stashed in regs, dumped over x buffer
//           - 27-neighbor attention from LDS (round-5 proven layout/code)
//           No Q/K/V global round-trip.

#define NVOX 64000   // 40*40*40
#define DIM 40
#define CCH 64
#define HEADS 4
#define HD 16

#define TZ 2
#define TY 4
#define TX 8
#define NH 240            // 4*6*10 halo voxels
#define XSTR 72           // x-halo row stride in halfwords (144 B, 16B-mult)

typedef __attribute__((ext_vector_type(8))) short bf16x8;
typedef __attribute__((ext_vector_type(4))) float f32x4;

__device__ __forceinline__ unsigned short f2bf(float f) {
    unsigned int u = __float_as_uint(f);
    u += 0x7fffu + ((u >> 16) & 1u);          // round-to-nearest-even
    return (unsigned short)(u >> 16);
}
__device__ __forceinline__ unsigned int pk2(float a, float b) {
    return (unsigned int)f2bf(a) | ((unsigned int)f2bf(b) << 16);
}
__device__ __forceinline__ float blo(unsigned int v) { return __uint_as_float(v << 16); }
__device__ __forceinline__ float bhi(unsigned int v) { return __uint_as_float(v & 0xffff0000u); }

__global__ __launch_bounds__(256) void pack_kernel(
    const float* __restrict__ Wq, const float* __restrict__ bq,
    const float* __restrict__ Wk, const float* __restrict__ bk,
    const float* __restrict__ Wv, const float* __restrict__ bv,
    unsigned short* __restrict__ Wbf, float* __restrict__ biasp)
{
    const int t = blockIdx.x * 256 + threadIdx.x;
    if (t < 12288) {
        const int r = t >> 6, c = t & 63;
        const float val = (r < 64)  ? 0.25f * Wq[r * 64 + c]
                        : (r < 128) ? Wk[(r - 64) * 64 + c]
                                    : Wv[(r - 128) * 64 + c];
        Wbf[t] = f2bf(val);
    }
    if (t < 192) {
        biasp[t] = (t < 64)  ? 0.25f * bq[t]
                 : (t < 128) ? bk[t - 64]
                             : bv[t - 128];
    }
}

__global__ __launch_bounds__(256) void fused_kernel(
    const float* __restrict__ x,
    const unsigned short* __restrict__ Wbf, const float* __restrict__ biasp,
    float* __restrict__ out)
{
    // xv: x halo bf16 [240][72]; after proj, reused as V [h][half][240][8]
    __shared__ __align__(16) unsigned short xv[NH * XSTR];   // 34560 B
    __shared__ __align__(16) unsigned short Kl[15360];       // 30720 B [h][half][240][8]
    __shared__ __align__(16) unsigned short Ql[4096];        //  8192 B [h][j4][64][4]

    const int tid = threadIdx.x;
    const int bid = blockIdx.x;            // 5*10*20 = 1000 tiles
    const int tx = bid % 5;
    const int ty = (bid / 5) % 10;
    const int tz = bid / 50;
    const int z0 = tz * TZ - 1, y0 = ty * TY - 1, x0 = tx * TX - 1;

    // ---- Stage x halo: thread = halo voxel, 32 channel-pairs ----
    if (tid < NH) {
        const int hz = tid / 60; const int r = tid - hz * 60;
        const int hy = r / 10;   const int hx = r - hy * 10;
        const int gz = min(max(z0 + hz, 0), DIM - 1);
        const int gy = min(max(y0 + hy, 0), DIM - 1);
        const int gx = min(max(x0 + hx, 0), DIM - 1);
        const float* xp = x + (gz * DIM + gy) * DIM + gx;
        unsigned short* dst = &xv[tid * XSTR];
        #pragma unroll
        for (int cp = 0; cp < 32; ++cp) {
            const float a = xp[(2 * cp) * NVOX];
            const float b = xp[(2 * cp + 1) * NVOX];
            *reinterpret_cast<unsigned int*>(&dst[2 * cp]) = pk2(a, b);
        }
    }
    __syncthreads();

    const int lane = tid & 63;
    const int w    = tid >> 6;      // wave id
    const int l15  = lane & 15;
    const int l4   = lane >> 4;

    // ---- Q for own 64 voxels (wave w -> own-tile w), gathered B-frags ----
    {
        const int ov = w * 16 + l15;
        const int lz = ov >> 5, ly = (ov >> 3) & 3, lx = ov & 7;
        const int mq = (lz + 1) * 60 + (ly + 1) * 10 + (lx + 1);
        const bf16x8 bx0 = *reinterpret_cast<const bf16x8*>(&xv[mq * XSTR + l4 * 8]);
        const bf16x8 bx1 = *reinterpret_cast<const bf16x8*>(&xv[mq * XSTR + 32 + l4 * 8]);
        #pragma unroll
        for (int rb = 0; rb < 4; ++rb) {
            const int row = rb * 16 + l15;
            const bf16x8 a0 = *reinterpret_cast<const bf16x8*>(&Wbf[row * 64 + l4 * 8]);
            const bf16x8 a1 = *reinterpret_cast<const bf16x8*>(&Wbf[row * 64 + 32 + l4 * 8]);
            f32x4 acc = {0.f, 0.f, 0.f, 0.f};
            acc = __builtin_amdgcn_mfma_f32_16x16x32_bf16(a0, bx0, acc, 0, 0, 0);
            acc = __builtin_amdgcn_mfma_f32_16x16x32_bf16(a1, bx1, acc, 0, 0, 0);
            const float4 bs = *reinterpret_cast<const float4*>(&biasp[rb * 16 + l4 * 4]);
            // Ql[h=rb][j4=l4][vox=ov][4]
            *reinterpret_cast<uint2*>(&Ql[((rb * 4 + l4) * 64 + ov) * 4]) =
                make_uint2(pk2(acc[0] + bs.x, acc[1] + bs.y),
                           pk2(acc[2] + bs.z, acc[3] + bs.w));
        }
    }

    // ---- K (to Kl) and V (to reg stash) for all 240 halo voxels ----
    unsigned int vst[4][4][2];
    #pragma unroll
    for (int i = 0; i < 4; ++i) {
        const int T = w + 4 * i;               // halo vox-tile 0..14
        if (T < 15) {
            const int vox = T * 16 + l15;
            const bf16x8 bx0 = *reinterpret_cast<const bf16x8*>(&xv[vox * XSTR + l4 * 8]);
            const bf16x8 bx1 = *reinterpret_cast<const bf16x8*>(&xv[vox * XSTR + 32 + l4 * 8]);
            #pragma unroll
            for (int rb = 0; rb < 4; ++rb) {
                const int rowa = rb * 16 + l15;
                // K = W rows 64..127
                {
                    const bf16x8 a0 = *reinterpret_cast<const bf16x8*>(
                        &Wbf[(64 + rowa) * 64 + l4 * 8]);
                    const bf16x8 a1 = *reinterpret_cast<const bf16x8*>(
                        &Wbf[(64 + rowa) * 64 + 32 + l4 * 8]);
                    f32x4 acc = {0.f, 0.f, 0.f, 0.f};
                    acc = __builtin_amdgcn_mfma_f32_16x16x32_bf16(a0, bx0, acc, 0, 0, 0);
                    acc = __builtin_amdgcn_mfma_f32_16x16x32_bf16(a1, bx1, acc, 0, 0, 0);
                    const float4 bs = *reinterpret_cast<const float4*>(
                        &biasp[64 + rb * 16 + l4 * 4]);
                    // Kl[h=rb][half=l4>>1][vox][(l4&1)*4 ..]
                    *reinterpret_cast<uint2*>(
                        &Kl[rb * 3840 + (l4 >> 1) * 1920 + vox * 8 + (l4 & 1) * 4]) =
                        make_uint2(pk2(acc[0] + bs.x, acc[1] + bs.y),
                                   pk2(acc[2] + bs.z, acc[3] + bs.w));
                }
                // V = W rows 128..191 -> regs
                {
                    const bf16x8 a0 = *reinterpret_cast<const bf16x8*>(
                        &Wbf[(128 + rowa) * 64 + l4 * 8]);
                    const bf16x8 a1 = *reinterpret_cast<const bf16x8*>(
                        &Wbf[(128 + rowa) * 64 + 32 + l4 * 8]);
                    f32x4 acc = {0.f, 0.f, 0.f, 0.f};
                    acc = __builtin_amdgcn_mfma_f32_16x16x32_bf16(a0, bx0, acc, 0, 0, 0);
                    acc = __builtin_amdgcn_mfma_f32_16x16x32_bf16(a1, bx1, acc, 0, 0, 0);
                    const float4 bs = *reinterpret_cast<const float4*>(
                        &biasp[128 + rb * 16 + l4 * 4]);
                    vst[i][rb][0] = pk2(acc[0] + bs.x, acc[1] + bs.y);
                    vst[i][rb][1] = pk2(acc[2] + bs.z, acc[3] + bs.w);
                }
            }
        }
    }
    __syncthreads();           // all xv reads + Kl/Ql writes complete

    // ---- Dump V stash over the x buffer: xv -> [h][half][240][8] ----
    #pragma unroll
    for (int i = 0; i < 4; ++i) {
        const int T = w + 4 * i;
        if (T < 15) {
            const int vox = T * 16 + l15;
            #pragma unroll
            for (int rb = 0; rb < 4; ++rb)
                *reinterpret_cast<uint2*>(
                    &xv[rb * 3840 + (l4 >> 1) * 1920 + vox * 8 + (l4 & 1) * 4]) =
                    make_uint2(vst[i][rb][0], vst[i][rb][1]);
        }
    }
    __syncthreads();

    // ---- Attention: thread = (own voxel, head) ----
    const int vox = tid & 63;
    const int h   = tid >> 6;
    const int lz = vox >> 5, ly = (vox >> 3) & 3, lx = vox & 7;
    const int gz = tz * TZ + lz, gy = ty * TY + ly, gx = tx * TX + lx;
    const int n = (gz * DIM + gy) * DIM + gx;

    float ql[16];
    #pragma unroll
    for (int j4 = 0; j4 < 4; ++j4) {
        const uint2 qp = *reinterpret_cast<const uint2*>(
            &Ql[((h * 4 + j4) * 64 + vox) * 4]);
        ql[4 * j4 + 0] = blo(qp.x); ql[4 * j4 + 1] = bhi(qp.x);
        ql[4 * j4 + 2] = blo(qp.y); ql[4 * j4 + 3] = bhi(qp.y);
    }

    const int mlc = (lz + 1) * 60 + (ly + 1) * 10 + (lx + 1);
    const uint4* kb = reinterpret_cast<const uint4*>(&Kl[h * 3840 + mlc * 8]);
    const uint4* vb = reinterpret_cast<const uint4*>(&xv[h * 3840 + mlc * 8]);

    float s = 0.0f;
    float av[16];
    #pragma unroll
    for (int j = 0; j < 16; ++j) av[j] = 0.0f;

    #pragma unroll
    for (int dz = -1; dz <= 1; ++dz) {
        #pragma unroll
        for (int dy = -1; dy <= 1; ++dy) {
            #pragma unroll
            for (int dx = -1; dx <= 1; ++dx) {
                const int off = dz * 60 + dy * 10 + dx;
                const uint4 ka = kb[off];          // ch 0-7  (4x bf16x2)
                const uint4 kc = kb[off + 240];    // ch 8-15

                float lg;
                lg  = ql[0]  * blo(ka.x) + ql[1]  * bhi(ka.x);
                lg += ql[2]  * blo(ka.y) + ql[3]  * bhi(ka.y);
                lg += ql[4]  * blo(ka.z) + ql[5]  * bhi(ka.z);
                lg += ql[6]  * blo(ka.w) + ql[7]  * bhi(ka.w);
                lg += ql[8]  * blo(kc.x) + ql[9]  * bhi(kc.x);
                lg += ql[10] * blo(kc.y) + ql[11] * bhi(kc.y);
                lg += ql[12] * blo(kc.z) + ql[13] * bhi(kc.z);
                lg += ql[14] * blo(kc.w) + ql[15] * bhi(kc.w);

                // max-free softmax: logits ~N(0,1), e^|lg| far from f32 limits
                const float e = __expf(lg);
                s += e;

                const uint4 va = vb[off];
                const uint4 vc = vb[off + 240];
                av[0]  = fmaf(e, blo(va.x), av[0]);
                av[1]  = fmaf(e, bhi(va.x), av[1]);
                av[2]  = fmaf(e, blo(va.y), av[2]);
                av[3]  = fmaf(e, bhi(va.y), av[3]);
                av[4]  = fmaf(e, blo(va.z), av[4]);
                av[5]  = fmaf(e, bhi(va.z), av[5]);
                av[6]  = fmaf(e, blo(va.w), av[6]);
                av[7]  = fmaf(e, bhi(va.w), av[7]);
                av[8]  = fmaf(e, blo(vc.x), av[8]);
                av[9]  = fmaf(e, bhi(vc.x), av[9]);
                av[10] = fmaf(e, blo(vc.y), av[10]);
                av[11] = fmaf(e, bhi(vc.y), av[11]);
                av[12] = fmaf(e, blo(vc.z), av[12]);
                av[13] = fmaf(e, bhi(vc.z), av[13]);
                av[14] = fmaf(e, blo(vc.w), av[14]);
                av[15] = fmaf(e, bhi(vc.w), av[15]);
            }
        }
    }

    const float rs = 1.0f / s;
    const int cb = h * HD;
    #pragma unroll
    for (int j = 0; j < 16; ++j) {
        const size_t idx = (size_t)(cb + j) * NVOX + n;
        out[idx] = x[idx] + av[j] * rs;
    }
}

extern "C" void kernel_launch(void* const* d_in, const int* in_sizes, int n_in,
                              void* d_out, int out_size, void* d_ws, size_t ws_size,
                              hipStream_t stream) {
    const float* x  = (const float*)d_in[0];
    // d_in[1] = cemb (unused by the reference)
    const float* Wq = (const float*)d_in[2];
    const float* bq = (const float*)d_in[3];
    const float* Wk = (const float*)d_in[4];
    const float* bk = (const float*)d_in[5];
    const float* Wv = (const float*)d_in[6];
    const float* bv = (const float*)d_in[7];
    float* out = (float*)d_out;

    unsigned short* Wbf = (unsigned short*)d_ws;       // bf16 [192][64]
    float* biasp = (float*)(Wbf + 192 * 64);           // f32 [192]

    pack_kernel<<<dim3(48), dim3(256), 0, stream>>>(
        Wq, bq, Wk, bk, Wv, bv, Wbf, biasp);
    fused_kernel<<<dim3(1000), dim3(256), 0, stream>>>(
        x, Wbf, biasp, out);
}

// Round 8
// 43.980 us; speedup vs baseline: 1.7514x; 1.7514x over previous
//
#include <hip/hip_runtime.h>
#include <hip/hip_bf16.h>

// Local attention block: 40^3 volume, C=64, 4 heads of hd=16, 3x3x3 window,
// replicate padding, residual add. f32 in/out.
//
// Kernel 1: proj via MFMA 16x16x32 bf16 with W-pack folded in:
//           per block, W f32 -> bf16 LDS [chunk][192][8] (Q rows pre-scaled
//           1/4), x-tile -> LDS [chunk][64][8]; all LDS vector ops at 16 B
//           lane stride (round-5-proven conflict-free). Q,K,V -> bf16 [N][64].
// Kernel 2: LDS-staged tiled attention (round-5 proven layout), Q bf16,
//           merged K/V staging for MLP.
// Both: bijective XCD swizzle (1000 % 8 == 0) so proj/attn tile i share L2.

#define NVOX 64000   // 40*40*40
#define DIM 40
#define CCH 64
#define HEADS 4
#define HD 16

#define TZ 2
#define TY 4
#define TX 8
#define NH 240            // 4*6*10 halo voxels

typedef __attribute__((ext_vector_type(8))) short bf16x8;
typedef __attribute__((ext_vector_type(4))) float f32x4;

__device__ __forceinline__ unsigned short f2bf(float f) {
    unsigned int u = __float_as_uint(f);
    u += 0x7fffu + ((u >> 16) & 1u);          // round-to-nearest-even
    return (unsigned short)(u >> 16);
}
__device__ __forceinline__ unsigned int pk2(float a, float b) {
    return (unsigned int)f2bf(a) | ((unsigned int)f2bf(b) << 16);
}
__device__ __forceinline__ float blo(unsigned int v) { return __uint_as_float(v << 16); }
__device__ __forceinline__ float bhi(unsigned int v) { return __uint_as_float(v & 0xffff0000u); }

__device__ __forceinline__ int xcd_swz(int b) {   // bijective, 1000 % 8 == 0
    return (b & 7) * 125 + (b >> 3);
}

__global__ __launch_bounds__(256) void proj_mfma(
    const float* __restrict__ x,
    const float* __restrict__ Wq, const float* __restrict__ bq,
    const float* __restrict__ Wk, const float* __restrict__ bk,
    const float* __restrict__ Wv, const float* __restrict__ bv,
    unsigned short* __restrict__ Qg, unsigned short* __restrict__ Kg,
    unsigned short* __restrict__ Vg)
{
    // All LDS tiles 16B-granular: [chunk][row/vox][8 ch] -> 16 B lane stride.
    __shared__ __align__(16) unsigned short Wl[8 * 192 * 8];  // 24576 B
    __shared__ __align__(16) unsigned short xl[8 * 64 * 8];   //  8192 B
    __shared__ __align__(16) float bl[192];                   //   768 B

    const int tid = threadIdx.x;
    const int bid = xcd_swz((int)blockIdx.x);
    const int n0 = bid * 64;

    // ---- Stage W + bias: thread t<192 owns one output row ----
    if (tid < 192) {
        const float* Wsrc; const float* bsrc; float sc; int r;
        if (tid < 64)       { Wsrc = Wq; bsrc = bq; sc = 0.25f; r = tid; }
        else if (tid < 128) { Wsrc = Wk; bsrc = bk; sc = 1.0f;  r = tid - 64; }
        else                { Wsrc = Wv; bsrc = bv; sc = 1.0f;  r = tid - 128; }
        const float4* wr = reinterpret_cast<const float4*>(Wsrc + r * 64);
        #pragma unroll
        for (int c = 0; c < 8; ++c) {            // chunk = 8 ch = 2 float4
            const float4 f0 = wr[2 * c], f1 = wr[2 * c + 1];
            *reinterpret_cast<uint4*>(&Wl[(c * 192 + tid) * 8]) =
                make_uint4(pk2(sc * f0.x, sc * f0.y), pk2(sc * f0.z, sc * f0.w),
                           pk2(sc * f1.x, sc * f1.y), pk2(sc * f1.z, sc * f1.w));
        }
        bl[tid] = sc * bsrc[r];
    }
    // ---- Stage x tile: 512 items = (chunk, vox) ----
    #pragma unroll
    for (int i = 0; i < 2; ++i) {
        const int item = tid + i * 256;
        const int v = item & 63, c = item >> 6;      // c: 0..3 then 4..7
        float f[8];
        #pragma unroll
        for (int j = 0; j < 8; ++j)
            f[j] = x[(c * 8 + j) * NVOX + n0 + v];   // coalesced across lanes
        *reinterpret_cast<uint4*>(&xl[(c * 64 + v) * 8]) =
            make_uint4(pk2(f[0], f[1]), pk2(f[2], f[3]),
                       pk2(f[4], f[5]), pk2(f[6], f[7]));
    }
    __syncthreads();

    const int lane = tid & 63;
    const int wv   = tid >> 6;
    const int l15  = lane & 15;
    const int l4   = lane >> 4;
    const int vox  = wv * 16 + l15;
    const int n    = n0 + vox;               // D col = lane&15 -> voxel

    const bf16x8 bx0 = *reinterpret_cast<const bf16x8*>(&xl[(l4 * 64 + vox) * 8]);
    const bf16x8 bx1 = *reinterpret_cast<const bf16x8*>(&xl[((l4 + 4) * 64 + vox) * 8]);

    #pragma unroll
    for (int rb = 0; rb < 12; ++rb) {
        const int row = rb * 16 + l15;       // A row, k-chunks l4 / l4+4
        const bf16x8 a0 = *reinterpret_cast<const bf16x8*>(&Wl[(l4 * 192 + row) * 8]);
        const bf16x8 a1 = *reinterpret_cast<const bf16x8*>(&Wl[((l4 + 4) * 192 + row) * 8]);

        f32x4 acc = {0.f, 0.f, 0.f, 0.f};
        acc = __builtin_amdgcn_mfma_f32_16x16x32_bf16(a0, bx0, acc, 0, 0, 0);
        acc = __builtin_amdgcn_mfma_f32_16x16x32_bf16(a1, bx1, acc, 0, 0, 0);

        const int r0 = rb * 16 + l4 * 4;     // D rows r0..r0+3 for this lane
        const float4 bs = *reinterpret_cast<const float4*>(&bl[r0]);
        const int rr = r0 & 63;              // row within its matrix
        unsigned short* og = (rb < 4) ? Qg : (rb < 8) ? Kg : Vg;
        *reinterpret_cast<uint2*>(&og[(size_t)n * CCH + rr]) =
            make_uint2(pk2(acc[0] + bs.x, acc[1] + bs.y),
                       pk2(acc[2] + bs.z, acc[3] + bs.w));
    }
}

__global__ __launch_bounds__(256) void attn_kernel(
    const float* __restrict__ x,
    const unsigned short* __restrict__ Qg, const unsigned short* __restrict__ Kg,
    const unsigned short* __restrict__ Vg,
    float* __restrict__ out)
{
    // LDS: [head][half(8ch)][240 halo voxels][8 bf16] -> 16 B lane stride
    __shared__ __align__(16) unsigned short Kl[15360];
    __shared__ __align__(16) unsigned short Vl[15360];

    const int tid = threadIdx.x;
    const int bid = xcd_swz((int)blockIdx.x);   // 5*10*20 = 1000 tiles
    const int tx = bid % 5;
    const int ty = (bid / 5) % 10;
    const int tz = bid / 50;
    const int z0 = tz * TZ - 1, y0 = ty * TY - 1, x0 = tx * TX - 1;

    // ---- Own (voxel, head); issue Q load first so it hides under staging ----
    const int vox = tid & 63;
    const int h   = tid >> 6;
    const int lz = vox >> 5, ly = (vox >> 3) & 3, lx = vox & 7;
    const int gz = tz * TZ + lz, gy = ty * TY + ly, gx = tx * TX + lx;
    const int n = (gz * DIM + gy) * DIM + gx;

    const uint4 q01 = *reinterpret_cast<const uint4*>(&Qg[(size_t)n * CCH + h * HD]);
    const uint4 q23 = *reinterpret_cast<const uint4*>(&Qg[(size_t)n * CCH + h * HD + 8]);

    // ---- Stage K+V halo together: 1920 uint4 parts each ----
    #pragma unroll
    for (int i = 0; i < 8; ++i) {
        const int cc = tid + i * 256;
        if (cc < NH * 8) {
            const int ml = cc >> 3, part = cc & 7;
            const int hz = ml / 60; const int r = ml - hz * 60;
            const int hy = r / 10;  const int hx = r - hy * 10;
            const int sz = min(max(z0 + hz, 0), DIM - 1);
            const int sy = min(max(y0 + hy, 0), DIM - 1);
            const int sx = min(max(x0 + hx, 0), DIM - 1);
            const int ns = (sz * DIM + sy) * DIM + sx;
            const uint4 dk = *reinterpret_cast<const uint4*>(
                &Kg[(size_t)ns * CCH + part * 8]);
            const uint4 dv = *reinterpret_cast<const uint4*>(
                &Vg[(size_t)ns * CCH + part * 8]);
            const int h2 = part >> 1, half = part & 1;
            const int dst = h2 * 3840 + half * 1920 + ml * 8;
            *reinterpret_cast<uint4*>(&Kl[dst]) = dk;
            *reinterpret_cast<uint4*>(&Vl[dst]) = dv;
        }
    }
    __syncthreads();

    float ql[16];
    ql[0]  = blo(q01.x); ql[1]  = bhi(q01.x);
    ql[2]  = blo(q01.y); ql[3]  = bhi(q01.y);
    ql[4]  = blo(q01.z); ql[5]  = bhi(q01.z);
    ql[6]  = blo(q01.w); ql[7]  = bhi(q01.w);
    ql[8]  = blo(q23.x); ql[9]  = bhi(q23.x);
    ql[10] = blo(q23.y); ql[11] = bhi(q23.y);
    ql[12] = blo(q23.z); ql[13] = bhi(q23.z);
    ql[14] = blo(q23.w); ql[15] = bhi(q23.w);

    const int mlc = (lz + 1) * 60 + (ly + 1) * 10 + (lx + 1);
    const uint4* kb = reinterpret_cast<const uint4*>(&Kl[h * 3840 + mlc * 8]);
    const uint4* vb = reinterpret_cast<const uint4*>(&Vl[h * 3840 + mlc * 8]);

    float s = 0.0f;
    float av[16];
    #pragma unroll
    for (int j = 0; j < 16; ++j) av[j] = 0.0f;

    #pragma unroll
    for (int dz = -1; dz <= 1; ++dz) {
        #pragma unroll
        for (int dy = -1; dy <= 1; ++dy) {
            #pragma unroll
            for (int dx = -1; dx <= 1; ++dx) {
                const int off = dz * 60 + dy * 10 + dx;
                const uint4 ka = kb[off];          // ch 0-7  (4x bf16x2)
                const uint4 kc = kb[off + 240];    // ch 8-15

                float lg;
                lg  = ql[0]  * blo(ka.x) + ql[1]  * bhi(ka.x);
                lg += ql[2]  * blo(ka.y) + ql[3]  * bhi(ka.y);
                lg += ql[4]  * blo(ka.z) + ql[5]  * bhi(ka.z);
                lg += ql[6]  * blo(ka.w) + ql[7]  * bhi(ka.w);
                lg += ql[8]  * blo(kc.x) + ql[9]  * bhi(kc.x);
                lg += ql[10] * blo(kc.y) + ql[11] * bhi(kc.y);
                lg += ql[12] * blo(kc.z) + ql[13] * bhi(kc.z);
                lg += ql[14] * blo(kc.w) + ql[15] * bhi(kc.w);

                // max-free softmax: logits ~N(0,1), e^|lg| far from f32 limits
                const float e = __expf(lg);
                s += e;

                const uint4 va = vb[off];
                const uint4 vc = vb[off + 240];
                av[0]  = fmaf(e, blo(va.x), av[0]);
                av[1]  = fmaf(e, bhi(va.x), av[1]);
                av[2]  = fmaf(e, blo(va.y), av[2]);
                av[3]  = fmaf(e, bhi(va.y), av[3]);
                av[4]  = fmaf(e, blo(va.z), av[4]);
                av[5]  = fmaf(e, bhi(va.z), av[5]);
                av[6]  = fmaf(e, blo(va.w), av[6]);
                av[7]  = fmaf(e, bhi(va.w), av[7]);
                av[8]  = fmaf(e, blo(vc.x), av[8]);
                av[9]  = fmaf(e, bhi(vc.x), av[9]);
                av[10] = fmaf(e, blo(vc.y), av[10]);
                av[11] = fmaf(e, bhi(vc.y), av[11]);
                av[12] = fmaf(e, blo(vc.z), av[12]);
                av[13] = fmaf(e, bhi(vc.z), av[13]);
                av[14] = fmaf(e, blo(vc.w), av[14]);
                av[15] = fmaf(e, bhi(vc.w), av[15]);
            }
        }
    }

    const float rs = 1.0f / s;
    const int cb = h * HD;
    #pragma unroll
    for (int j = 0; j < 16; ++j) {
        const size_t idx = (size_t)(cb + j) * NVOX + n;
        out[idx] = x[idx] + av[j] * rs;
    }
}

extern "C" void kernel_launch(void* const* d_in, const int* in_sizes, int n_in,
                              void* d_out, int out_size, void* d_ws, size_t ws_size,
                              hipStream_t stream) {
    const float* x  = (const float*)d_in[0];
    // d_in[1] = cemb (unused by the reference)
    const float* Wq = (const float*)d_in[2];
    const float* bq = (const float*)d_in[3];
    const float* Wk = (const float*)d_in[4];
    const float* bk = (const float*)d_in[5];
    const float* Wv = (const float*)d_in[6];
    const float* bv = (const float*)d_in[7];
    float* out = (float*)d_out;

    unsigned short* Qg = (unsigned short*)d_ws;        // bf16 [N][64]
    unsigned short* Kg = Qg + (size_t)NVOX * CCH;      // bf16 [N][64]
    unsigned short* Vg = Kg + (size_t)NVOX * CCH;      // bf16 [N][64]

    proj_mfma<<<dim3(1000), dim3(256), 0, stream>>>(
        x, Wq, bq, Wk, bk, Wv, bv, Qg, Kg, Vg);
    attn_kernel<<<dim3(1000), dim3(256), 0, stream>>>(
        x, Qg, Kg, Vg, out);
}

// Round 9
// 39.961 us; speedup vs baseline: 1.9275x; 1.1006x over previous
//
#include <hip/hip_runtime.h>
#include <hip/hip_bf16.h>

// Local attention block: 40^3 volume, C=64, 4 heads of hd=16, 3x3x3 window,
// replicate padding, residual add. f32 in/out.
//
// Kernel 1: proj via MFMA 16x16x32 bf16 with W-pack folded in (round-8,
//           unchanged). Q,K,V -> bf16 [N][64], Q pre-scaled 1/4.
// Kernel 2: attention re-tiled for occupancy: block = (4x8x8 voxel tile,
//           ONE head). LDS = K+V halo (6x10x10=600 vox, 16 ch bf16) =
//           38.4 KB -> 4 blocks/CU (2x round-8 occupancy). 16B-lane-stride
//           layout (measured conflict-free). Max-free softmax.

#define NVOX 64000   // 40*40*40
#define DIM 40
#define CCH 64
#define HEADS 4
#define HD 16

// attn tile geometry (one head per block)
#define ATZ 4
#define ATY 8
#define ATX 8
#define AHZ 6
#define AHY 10
#define AHX 10
#define ANH 600           // 6*10*10 halo voxels

typedef __attribute__((ext_vector_type(8))) short bf16x8;
typedef __attribute__((ext_vector_type(4))) float f32x4;

__device__ __forceinline__ unsigned short f2bf(float f) {
    unsigned int u = __float_as_uint(f);
    u += 0x7fffu + ((u >> 16) & 1u);          // round-to-nearest-even
    return (unsigned short)(u >> 16);
}
__device__ __forceinline__ unsigned int pk2(float a, float b) {
    return (unsigned int)f2bf(a) | ((unsigned int)f2bf(b) << 16);
}
__device__ __forceinline__ float blo(unsigned int v) { return __uint_as_float(v << 16); }
__device__ __forceinline__ float bhi(unsigned int v) { return __uint_as_float(v & 0xffff0000u); }

__device__ __forceinline__ int xcd_swz(int b) {   // bijective, 1000 % 8 == 0
    return (b & 7) * 125 + (b >> 3);
}

__global__ __launch_bounds__(256) void proj_mfma(
    const float* __restrict__ x,
    const float* __restrict__ Wq, const float* __restrict__ bq,
    const float* __restrict__ Wk, const float* __restrict__ bk,
    const float* __restrict__ Wv, const float* __restrict__ bv,
    unsigned short* __restrict__ Qg, unsigned short* __restrict__ Kg,
    unsigned short* __restrict__ Vg)
{
    // All LDS tiles 16B-granular: [chunk][row/vox][8 ch] -> 16 B lane stride.
    __shared__ __align__(16) unsigned short Wl[8 * 192 * 8];  // 24576 B
    __shared__ __align__(16) unsigned short xl[8 * 64 * 8];   //  8192 B
    __shared__ __align__(16) float bl[192];                   //   768 B

    const int tid = threadIdx.x;
    const int bid = xcd_swz((int)blockIdx.x);
    const int n0 = bid * 64;

    // ---- Stage W + bias: thread t<192 owns one output row ----
    if (tid < 192) {
        const float* Wsrc; const float* bsrc; float sc; int r;
        if (tid < 64)       { Wsrc = Wq; bsrc = bq; sc = 0.25f; r = tid; }
        else if (tid < 128) { Wsrc = Wk; bsrc = bk; sc = 1.0f;  r = tid - 64; }
        else                { Wsrc = Wv; bsrc = bv; sc = 1.0f;  r = tid - 128; }
        const float4* wr = reinterpret_cast<const float4*>(Wsrc + r * 64);
        #pragma unroll
        for (int c = 0; c < 8; ++c) {            // chunk = 8 ch = 2 float4
            const float4 f0 = wr[2 * c], f1 = wr[2 * c + 1];
            *reinterpret_cast<uint4*>(&Wl[(c * 192 + tid) * 8]) =
                make_uint4(pk2(sc * f0.x, sc * f0.y), pk2(sc * f0.z, sc * f0.w),
                           pk2(sc * f1.x, sc * f1.y), pk2(sc * f1.z, sc * f1.w));
        }
        bl[tid] = sc * bsrc[r];
    }
    // ---- Stage x tile: 512 items = (chunk, vox) ----
    #pragma unroll
    for (int i = 0; i < 2; ++i) {
        const int item = tid + i * 256;
        const int v = item & 63, c = item >> 6;      // c: 0..3 then 4..7
        float f[8];
        #pragma unroll
        for (int j = 0; j < 8; ++j)
            f[j] = x[(c * 8 + j) * NVOX + n0 + v];   // coalesced across lanes
        *reinterpret_cast<uint4*>(&xl[(c * 64 + v) * 8]) =
            make_uint4(pk2(f[0], f[1]), pk2(f[2], f[3]),
                       pk2(f[4], f[5]), pk2(f[6], f[7]));
    }
    __syncthreads();

    const int lane = tid & 63;
    const int wv   = tid >> 6;
    const int l15  = lane & 15;
    const int l4   = lane >> 4;
    const int vox  = wv * 16 + l15;
    const int n    = n0 + vox;               // D col = lane&15 -> voxel

    const bf16x8 bx0 = *reinterpret_cast<const bf16x8*>(&xl[(l4 * 64 + vox) * 8]);
    const bf16x8 bx1 = *reinterpret_cast<const bf16x8*>(&xl[((l4 + 4) * 64 + vox) * 8]);

    #pragma unroll
    for (int rb = 0; rb < 12; ++rb) {
        const int row = rb * 16 + l15;       // A row, k-chunks l4 / l4+4
        const bf16x8 a0 = *reinterpret_cast<const bf16x8*>(&Wl[(l4 * 192 + row) * 8]);
        const bf16x8 a1 = *reinterpret_cast<const bf16x8*>(&Wl[((l4 + 4) * 192 + row) * 8]);

        f32x4 acc = {0.f, 0.f, 0.f, 0.f};
        acc = __builtin_amdgcn_mfma_f32_16x16x32_bf16(a0, bx0, acc, 0, 0, 0);
        acc = __builtin_amdgcn_mfma_f32_16x16x32_bf16(a1, bx1, acc, 0, 0, 0);

        const int r0 = rb * 16 + l4 * 4;     // D rows r0..r0+3 for this lane
        const float4 bs = *reinterpret_cast<const float4*>(&bl[r0]);
        const int rr = r0 & 63;              // row within its matrix
        unsigned short* og = (rb < 4) ? Qg : (rb < 8) ? Kg : Vg;
        *reinterpret_cast<uint2*>(&og[(size_t)n * CCH + rr]) =
            make_uint2(pk2(acc[0] + bs.x, acc[1] + bs.y),
                       pk2(acc[2] + bs.z, acc[3] + bs.w));
    }
}

__global__ __launch_bounds__(256, 4) void attn_kernel(
    const float* __restrict__ x,
    const unsigned short* __restrict__ Qg, const unsigned short* __restrict__ Kg,
    const unsigned short* __restrict__ Vg,
    float* __restrict__ out)
{
    // LDS per matrix: [half(8ch)][600 halo voxels][8 bf16] -> 16 B lane stride
    __shared__ __align__(16) unsigned short Kl[2 * ANH * 8];   // 19200 B
    __shared__ __align__(16) unsigned short Vl[2 * ANH * 8];   // 19200 B

    const int tid = threadIdx.x;
    const int bid = xcd_swz((int)blockIdx.x);   // 250 tiles x 4 heads
    const int h    = bid & 3;
    const int tile = bid >> 2;
    const int tx = tile % 5;
    const int ty = (tile / 5) % 5;
    const int tz = tile / 25;
    const int z0 = tz * ATZ - 1, y0 = ty * ATY - 1, x0 = tx * ATX - 1;

    // ---- Own voxel; issue Q load first so it hides under staging ----
    const int vox = tid;                   // 256 voxels, one head
    const int lz = vox >> 6, ly = (vox >> 3) & 7, lx = vox & 7;
    const int gz = tz * ATZ + lz, gy = ty * ATY + ly, gx = tx * ATX + lx;
    const int n = (gz * DIM + gy) * DIM + gx;

    const uint4 q01 = *reinterpret_cast<const uint4*>(&Qg[(size_t)n * CCH + h * HD]);
    const uint4 q23 = *reinterpret_cast<const uint4*>(&Qg[(size_t)n * CCH + h * HD + 8]);

    // ---- Stage K+V halo: 600 items, 32 B of K + 32 B of V each ----
    #pragma unroll
    for (int i = 0; i < 3; ++i) {
        const int ml = tid + i * 256;
        if (ml < ANH) {
            const int hz = ml / 100; const int r = ml - hz * 100;
            const int hy = r / 10;   const int hx = r - hy * 10;
            const int sz = min(max(z0 + hz, 0), DIM - 1);
            const int sy = min(max(y0 + hy, 0), DIM - 1);
            const int sx = min(max(x0 + hx, 0), DIM - 1);
            const size_t base = (size_t)((sz * DIM + sy) * DIM + sx) * CCH + h * HD;
            const uint4 k0 = *reinterpret_cast<const uint4*>(&Kg[base]);
            const uint4 k1 = *reinterpret_cast<const uint4*>(&Kg[base + 8]);
            const uint4 v0 = *reinterpret_cast<const uint4*>(&Vg[base]);
            const uint4 v1 = *reinterpret_cast<const uint4*>(&Vg[base + 8]);
            *reinterpret_cast<uint4*>(&Kl[ml * 8])            = k0;
            *reinterpret_cast<uint4*>(&Kl[ANH * 8 + ml * 8])  = k1;
            *reinterpret_cast<uint4*>(&Vl[ml * 8])            = v0;
            *reinterpret_cast<uint4*>(&Vl[ANH * 8 + ml * 8])  = v1;
        }
    }
    __syncthreads();

    float ql[16];
    ql[0]  = blo(q01.x); ql[1]  = bhi(q01.x);
    ql[2]  = blo(q01.y); ql[3]  = bhi(q01.y);
    ql[4]  = blo(q01.z); ql[5]  = bhi(q01.z);
    ql[6]  = blo(q01.w); ql[7]  = bhi(q01.w);
    ql[8]  = blo(q23.x); ql[9]  = bhi(q23.x);
    ql[10] = blo(q23.y); ql[11] = bhi(q23.y);
    ql[12] = blo(q23.z); ql[13] = bhi(q23.z);
    ql[14] = blo(q23.w); ql[15] = bhi(q23.w);

    const int mlc = (lz + 1) * 100 + (ly + 1) * 10 + (lx + 1);
    const uint4* kb = reinterpret_cast<const uint4*>(Kl) + mlc;
    const uint4* vb = reinterpret_cast<const uint4*>(Vl) + mlc;

    float s = 0.0f;
    float av[16];
    #pragma unroll
    for (int j = 0; j < 16; ++j) av[j] = 0.0f;

    #pragma unroll
    for (int dz = -1; dz <= 1; ++dz) {
        #pragma unroll
        for (int dy = -1; dy <= 1; ++dy) {
            #pragma unroll
            for (int dx = -1; dx <= 1; ++dx) {
                const int off = dz * 100 + dy * 10 + dx;
                const uint4 ka = kb[off];          // ch 0-7  (4x bf16x2)
                const uint4 kc = kb[off + ANH];    // ch 8-15

                float lg;
                lg  = ql[0]  * blo(ka.x) + ql[1]  * bhi(ka.x);
                lg += ql[2]  * blo(ka.y) + ql[3]  * bhi(ka.y);
                lg += ql[4]  * blo(ka.z) + ql[5]  * bhi(ka.z);
                lg += ql[6]  * blo(ka.w) + ql[7]  * bhi(ka.w);
                lg += ql[8]  * blo(kc.x) + ql[9]  * bhi(kc.x);
                lg += ql[10] * blo(kc.y) + ql[11] * bhi(kc.y);
                lg += ql[12] * blo(kc.z) + ql[13] * bhi(kc.z);
                lg += ql[14] * blo(kc.w) + ql[15] * bhi(kc.w);

                // max-free softmax: logits ~N(0,1), e^|lg| far from f32 limits
                const float e = __expf(lg);
                s += e;

                const uint4 va = vb[off];
                const uint4 vc = vb[off + ANH];
                av[0]  = fmaf(e, blo(va.x), av[0]);
                av[1]  = fmaf(e, bhi(va.x), av[1]);
                av[2]  = fmaf(e, blo(va.y), av[2]);
                av[3]  = fmaf(e, bhi(va.y), av[3]);
                av[4]  = fmaf(e, blo(va.z), av[4]);
                av[5]  = fmaf(e, bhi(va.z), av[5]);
                av[6]  = fmaf(e, blo(va.w), av[6]);
                av[7]  = fmaf(e, bhi(va.w), av[7]);
                av[8]  = fmaf(e, blo(vc.x), av[8]);
                av[9]  = fmaf(e, bhi(vc.x), av[9]);
                av[10] = fmaf(e, blo(vc.y), av[10]);
                av[11] = fmaf(e, bhi(vc.y), av[11]);
                av[12] = fmaf(e, blo(vc.z), av[12]);
                av[13] = fmaf(e, bhi(vc.z), av[13]);
                av[14] = fmaf(e, blo(vc.w), av[14]);
                av[15] = fmaf(e, bhi(vc.w), av[15]);
            }
        }
    }

    const float rs = 1.0f / s;
    const int cb = h * HD;
    #pragma unroll
    for (int j = 0; j < 16; ++j) {
        const size_t idx = (size_t)(cb + j) * NVOX + n;
        out[idx] = x[idx] + av[j] * rs;
    }
}

extern "C" void kernel_launch(void* const* d_in, const int* in_sizes, int n_in,
                              void* d_out, int out_size, void* d_ws, size_t ws_size,
                              hipStream_t stream) {
    const float* x  = (const float*)d_in[0];
    // d_in[1] = cemb (unused by the reference)
    const float* Wq = (const float*)d_in[2];
    const float* bq = (const float*)d_in[3];
    const float* Wk = (const float*)d_in[4];
    const float* bk = (const float*)d_in[5];
    const float* Wv = (const float*)d_in[6];
    const float* bv = (const float*)d_in[7];
    float* out = (float*)d_out;

    unsigned short* Qg = (unsigned short*)d_ws;        // bf16 [N][64]
    unsigned short* Kg = Qg + (size_t)NVOX * CCH;      // bf16 [N][64]
    unsigned short* Vg = Kg + (size_t)NVOX * CCH;      // bf16 [N][64]

    proj_mfma<<<dim3(1000), dim3(256), 0, stream>>>(
        x, Wq, bq, Wk, bk, Wv, bv, Qg, Kg, Vg);
    attn_kernel<<<dim3(1000), dim3(256), 0, stream>>>(
        x, Qg, Kg, Vg, out);
}